// Round 2
// baseline (1433.726 us; speedup 1.0000x reference)
//
#include <hip/hip_runtime.h>

#define NROWS 2048      // S*N rows of the token matrix
#define NN    1024      // sequence length
#define DIMM  768
#define HEADS 16
#define CH    48        // per-head dim
#define CPAIR 128
#define KSPLIT 4        // attention k-range split
#define KCH   16        // attention k chunk

__device__ __forceinline__ float sigm(float x){ return 1.0f/(1.0f+__expf(-x)); }

// ---------------------------------------------------------------------------
// LayerNorm of single_repr (no affine) and single_proj (scale-only)
// ---------------------------------------------------------------------------
__global__ __launch_bounds__(256) void k_ln_single(
    const float* __restrict__ srep, const float* __restrict__ sproj,
    const float* __restrict__ sw, float* __restrict__ a_ln, float* __restrict__ s_ln)
{
    int r = blockIdx.x, t = threadIdx.x;
    const float* xa = srep  + (size_t)r*DIMM;
    const float* xs = sproj + (size_t)r*DIMM;
    float va[3], vs[3];
    float sa=0.f,qa=0.f,ss=0.f,qs=0.f;
    #pragma unroll
    for (int i=0;i<3;i++){ float x=xa[t+256*i]; va[i]=x; sa+=x; qa+=x*x; }
    #pragma unroll
    for (int i=0;i<3;i++){ float x=xs[t+256*i]; vs[i]=x; ss+=x; qs+=x*x; }
    #pragma unroll
    for (int off=32; off>=1; off>>=1){
        sa += __shfl_xor(sa,off); qa += __shfl_xor(qa,off);
        ss += __shfl_xor(ss,off); qs += __shfl_xor(qs,off);
    }
    __shared__ float red[16];
    int w = t>>6;
    if ((t&63)==0){ red[w*4+0]=sa; red[w*4+1]=qa; red[w*4+2]=ss; red[w*4+3]=qs; }
    __syncthreads();
    sa = red[0]+red[4]+red[8]+red[12];
    qa = red[1]+red[5]+red[9]+red[13];
    ss = red[2]+red[6]+red[10]+red[14];
    qs = red[3]+red[7]+red[11]+red[15];
    float mua=sa*(1.f/768.f), mus=ss*(1.f/768.f);
    float rva=rsqrtf(fmaxf(qa*(1.f/768.f)-mua*mua,0.f)+1e-5f);
    float rvs=rsqrtf(fmaxf(qs*(1.f/768.f)-mus*mus,0.f)+1e-5f);
    #pragma unroll
    for (int i=0;i<3;i++){
        int c=t+256*i;
        a_ln[(size_t)r*DIMM+c]=(va[i]-mua)*rva;
        s_ln[(size_t)r*DIMM+c]=(vs[i]-mus)*rvs*sw[c];
    }
}

// ---------------------------------------------------------------------------
// pair bias precompute
// ---------------------------------------------------------------------------
__global__ void k_pair_pre(const float* __restrict__ lnw, const float* __restrict__ lnb,
                           const float* __restrict__ wp, float* __restrict__ wpc,
                           float* __restrict__ csb)
{
    int t = threadIdx.x;
    for (int i=t;i<2048;i+=256) wpc[i] = lnw[i>>4]*wp[i];
    if (t<16){
        float cs=0.f,b0=0.f;
        for (int c=0;c<128;c++){ cs += lnw[c]*wp[c*16+t]; b0 += lnb[c]*wp[c*16+t]; }
        csb[t]=cs; csb[16+t]=b0;
    }
}

// ---------------------------------------------------------------------------
// pair bias: pb[h][i][j] = LN(pair[i,j,:]) @ w_pair[:,h] + INF*(mask[j]-1)
// ---------------------------------------------------------------------------
__global__ __launch_bounds__(256) void k_pair_bias(
    const float* __restrict__ pair, const float* __restrict__ wpc,
    const float* __restrict__ csb, const float* __restrict__ mask,
    float* __restrict__ pb)
{
    int row = blockIdx.x*256 + threadIdx.x;     // 0..N*N-1
    int j = row & (NN-1);
    const float* x = pair + (size_t)row*CPAIR;
    float y[128];
    float s=0.f, q=0.f;
    #pragma unroll
    for (int c4=0;c4<32;c4++){
        float4 v = *(const float4*)(x + 4*c4);
        y[4*c4]=v.x; y[4*c4+1]=v.y; y[4*c4+2]=v.z; y[4*c4+3]=v.w;
        s += v.x+v.y+v.z+v.w;
        q += v.x*v.x+v.y*v.y+v.z*v.z+v.w*v.w;
    }
    float mu = s*(1.f/128.f);
    float rs = rsqrtf(fmaxf(q*(1.f/128.f)-mu*mu,0.f)+1e-5f);
    float acc[16];
    #pragma unroll
    for (int h=0;h<16;h++) acc[h]=0.f;
    #pragma unroll
    for (int c=0;c<128;c++){
        float yc = y[c];
        const float4* wr = (const float4*)(wpc + c*16);
        float4 w0=wr[0], w1=wr[1], w2=wr[2], w3=wr[3];
        acc[0]+=yc*w0.x; acc[1]+=yc*w0.y; acc[2]+=yc*w0.z; acc[3]+=yc*w0.w;
        acc[4]+=yc*w1.x; acc[5]+=yc*w1.y; acc[6]+=yc*w1.z; acc[7]+=yc*w1.w;
        acc[8]+=yc*w2.x; acc[9]+=yc*w2.y; acc[10]+=yc*w2.z; acc[11]+=yc*w2.w;
        acc[12]+=yc*w3.x; acc[13]+=yc*w3.y; acc[14]+=yc*w3.z; acc[15]+=yc*w3.w;
    }
    float mb = 1e8f*(mask[j]-1.f);
    #pragma unroll
    for (int h=0;h<16;h++){
        float out = (acc[h]-mu*csb[h])*rs + csb[16+h] + mb;
        pb[((size_t)h<<20) + row] = out;
    }
}

// ---------------------------------------------------------------------------
// fused AdaLN: a = sigmoid(s_ln@gate_w + gate_b)*a_ln + s_ln@skip_w
// one pass over A, two B streams, 8-col strip
// ---------------------------------------------------------------------------
__global__ __launch_bounds__(256) void k_adaln(
    const float* __restrict__ A, const float* __restrict__ gw,
    const float* __restrict__ skw, const float* __restrict__ gb,
    const float* __restrict__ a_ln, float* __restrict__ outp)
{
    int row = blockIdx.x*256 + threadIdx.x;
    int col0 = blockIdx.y*8;
    const float* arow = A + (size_t)row*DIMM;
    float ag[8], as[8];
    #pragma unroll
    for (int i=0;i<8;i++){ ag[i]=0.f; as[i]=0.f; }
    for (int k4=0;k4<DIMM;k4+=4){
        float4 a4 = *(const float4*)(arow+k4);
        float av[4]={a4.x,a4.y,a4.z,a4.w};
        #pragma unroll
        for (int kk=0;kk<4;kk++){
            const float* g0 = gw  + (size_t)(k4+kk)*DIMM + col0;
            const float* s0 = skw + (size_t)(k4+kk)*DIMM + col0;
            float4 g1=*(const float4*)g0, g2=*(const float4*)(g0+4);
            float4 s1=*(const float4*)s0, s2=*(const float4*)(s0+4);
            float ak = av[kk];
            ag[0]+=ak*g1.x; ag[1]+=ak*g1.y; ag[2]+=ak*g1.z; ag[3]+=ak*g1.w;
            ag[4]+=ak*g2.x; ag[5]+=ak*g2.y; ag[6]+=ak*g2.z; ag[7]+=ak*g2.w;
            as[0]+=ak*s1.x; as[1]+=ak*s1.y; as[2]+=ak*s1.z; as[3]+=ak*s1.w;
            as[4]+=ak*s2.x; as[5]+=ak*s2.y; as[6]+=ak*s2.z; as[7]+=ak*s2.w;
        }
    }
    const float* al = a_ln + (size_t)row*DIMM + col0;
    float r[8];
    #pragma unroll
    for (int i=0;i<8;i++) r[i] = sigm(ag[i]+gb[col0+i])*al[i] + as[i];
    float4* out4 = (float4*)(outp + (size_t)row*DIMM + col0);
    out4[0]=make_float4(r[0],r[1],r[2],r[3]);
    out4[1]=make_float4(r[4],r[5],r[6],r[7]);
}

// ---------------------------------------------------------------------------
// q/k (z=0) and v/gate (z=1): two B streams per thread, 16-col strip
// q/k/v stored permuted [S,H,N,C]; q pre-scaled by 1/sqrt(C)
// ---------------------------------------------------------------------------
__global__ __launch_bounds__(256) void k_qkvg(
    const float* __restrict__ A,
    const float* __restrict__ wq, const float* __restrict__ wk,
    const float* __restrict__ wv, const float* __restrict__ wg,
    const float* __restrict__ bgate,
    float* __restrict__ qb, float* __restrict__ kb, float* __restrict__ vb,
    float* __restrict__ g)
{
    int row = blockIdx.x*256 + threadIdx.x;
    int col0 = blockIdx.y*16;
    int z = blockIdx.z;
    const float* B0 = z ? wv : wq;
    const float* B1 = z ? wg : wk;
    const float* arow = A + (size_t)row*DIMM;
    float a0[16], a1[16];
    #pragma unroll
    for (int i=0;i<16;i++){ a0[i]=0.f; a1[i]=0.f; }
    for (int k4=0;k4<DIMM;k4+=4){
        float4 a4 = *(const float4*)(arow+k4);
        float av[4]={a4.x,a4.y,a4.z,a4.w};
        #pragma unroll
        for (int kk=0;kk<4;kk++){
            const float* p0 = B0 + (size_t)(k4+kk)*DIMM + col0;
            const float* p1 = B1 + (size_t)(k4+kk)*DIMM + col0;
            float4 b00=*(const float4*)p0,     b01=*(const float4*)(p0+4);
            float4 b02=*(const float4*)(p0+8), b03=*(const float4*)(p0+12);
            float4 b10=*(const float4*)p1,     b11=*(const float4*)(p1+4);
            float4 b12=*(const float4*)(p1+8), b13=*(const float4*)(p1+12);
            float ak = av[kk];
            a0[0]+=ak*b00.x;  a0[1]+=ak*b00.y;  a0[2]+=ak*b00.z;  a0[3]+=ak*b00.w;
            a0[4]+=ak*b01.x;  a0[5]+=ak*b01.y;  a0[6]+=ak*b01.z;  a0[7]+=ak*b01.w;
            a0[8]+=ak*b02.x;  a0[9]+=ak*b02.y;  a0[10]+=ak*b02.z; a0[11]+=ak*b02.w;
            a0[12]+=ak*b03.x; a0[13]+=ak*b03.y; a0[14]+=ak*b03.z; a0[15]+=ak*b03.w;
            a1[0]+=ak*b10.x;  a1[1]+=ak*b10.y;  a1[2]+=ak*b10.z;  a1[3]+=ak*b10.w;
            a1[4]+=ak*b11.x;  a1[5]+=ak*b11.y;  a1[6]+=ak*b11.z;  a1[7]+=ak*b11.w;
            a1[8]+=ak*b12.x;  a1[9]+=ak*b12.y;  a1[10]+=ak*b12.z; a1[11]+=ak*b12.w;
            a1[12]+=ak*b13.x; a1[13]+=ak*b13.y; a1[14]+=ak*b13.z; a1[15]+=ak*b13.w;
        }
    }
    int s = row>>10, n = row&(NN-1);
    int h = col0/CH, cc0 = col0 - h*CH;          // 16 | 48, never straddles a head
    size_t pidx = (((size_t)(s*HEADS+h)*NN + n)*CH + cc0);
    if (z==0){
        const float scale = 0.14433756729740643f; // 1/sqrt(48)
        float4* qd = (float4*)(qb + pidx);
        float4* kd = (float4*)(kb + pidx);
        #pragma unroll
        for (int i=0;i<4;i++){
            qd[i]=make_float4(a0[4*i]*scale,a0[4*i+1]*scale,a0[4*i+2]*scale,a0[4*i+3]*scale);
            kd[i]=make_float4(a1[4*i],a1[4*i+1],a1[4*i+2],a1[4*i+3]);
        }
    } else {
        float4* vd = (float4*)(vb + pidx);
        const float4* b4 = (const float4*)(bgate+col0);
        float4* gd = (float4*)(g + (size_t)row*DIMM + col0);
        #pragma unroll
        for (int i=0;i<4;i++){
            vd[i]=make_float4(a0[4*i],a0[4*i+1],a0[4*i+2],a0[4*i+3]);
            float4 b=b4[i];
            gd[i]=make_float4(sigm(a1[4*i]+b.x),sigm(a1[4*i+1]+b.y),
                              sigm(a1[4*i+2]+b.z),sigm(a1[4*i+3]+b.w));
        }
    }
}

// ---------------------------------------------------------------------------
// o2 = o_g @ wo + bo  (8-col strip)
// ---------------------------------------------------------------------------
__global__ __launch_bounds__(256) void k_gemm_wo(
    const float* __restrict__ A, const float* __restrict__ B,
    const float* __restrict__ bo, float* __restrict__ C)
{
    int row = blockIdx.x*256 + threadIdx.x;
    int col0 = blockIdx.y*8;
    const float* arow = A + (size_t)row*DIMM;
    float acc[8];
    #pragma unroll
    for (int i=0;i<8;i++) acc[i]=0.f;
    for (int k4=0;k4<DIMM;k4+=4){
        float4 a4 = *(const float4*)(arow+k4);
        float av[4]={a4.x,a4.y,a4.z,a4.w};
        #pragma unroll
        for (int kk=0;kk<4;kk++){
            const float* p0 = B + (size_t)(k4+kk)*DIMM + col0;
            float4 b0=*(const float4*)p0, b1=*(const float4*)(p0+4);
            float ak = av[kk];
            acc[0]+=ak*b0.x; acc[1]+=ak*b0.y; acc[2]+=ak*b0.z; acc[3]+=ak*b0.w;
            acc[4]+=ak*b1.x; acc[5]+=ak*b1.y; acc[6]+=ak*b1.z; acc[7]+=ak*b1.w;
        }
    }
    float4* out4 = (float4*)(C + (size_t)row*DIMM + col0);
    out4[0]=make_float4(acc[0]+bo[col0],acc[1]+bo[col0+1],acc[2]+bo[col0+2],acc[3]+bo[col0+3]);
    out4[1]=make_float4(acc[4]+bo[col0+4],acc[5]+bo[col0+5],acc[6]+bo[col0+6],acc[7]+bo[col0+7]);
}

// out = sigmoid(o2@w_out + b_out) * o2  (8-col strip)
__global__ __launch_bounds__(256) void k_gemm_out(
    const float* __restrict__ A, const float* __restrict__ B,
    const float* __restrict__ bout, float* __restrict__ C)
{
    int row = blockIdx.x*256 + threadIdx.x;
    int col0 = blockIdx.y*8;
    const float* arow = A + (size_t)row*DIMM;
    float acc[8];
    #pragma unroll
    for (int i=0;i<8;i++) acc[i]=0.f;
    for (int k4=0;k4<DIMM;k4+=4){
        float4 a4 = *(const float4*)(arow+k4);
        float av[4]={a4.x,a4.y,a4.z,a4.w};
        #pragma unroll
        for (int kk=0;kk<4;kk++){
            const float* p0 = B + (size_t)(k4+kk)*DIMM + col0;
            float4 b0=*(const float4*)p0, b1=*(const float4*)(p0+4);
            float ak = av[kk];
            acc[0]+=ak*b0.x; acc[1]+=ak*b0.y; acc[2]+=ak*b0.z; acc[3]+=ak*b0.w;
            acc[4]+=ak*b1.x; acc[5]+=ak*b1.y; acc[6]+=ak*b1.z; acc[7]+=ak*b1.w;
        }
    }
    const float* al = A + (size_t)row*DIMM + col0;
    float r[8];
    #pragma unroll
    for (int i=0;i<8;i++) r[i] = sigm(acc[i]+bout[col0+i])*al[i];
    float4* out4 = (float4*)(C + (size_t)row*DIMM + col0);
    out4[0]=make_float4(r[0],r[1],r[2],r[3]);
    out4[1]=make_float4(r[4],r[5],r[6],r[7]);
}

// ---------------------------------------------------------------------------
// flash attention: lane = (q-row, 12-ch group); 4-lane shfl butterfly for
// scores; KSPLIT k-ranges. 8192 waves total.
// ---------------------------------------------------------------------------
__global__ __launch_bounds__(256) void k_attn(
    const float* __restrict__ qm, const float* __restrict__ km,
    const float* __restrict__ vm, const float* __restrict__ pb,
    float* __restrict__ pm, float* __restrict__ pl, float* __restrict__ po)
{
    int tid = threadIdx.x;
    int lane = tid & 63, wav = tid >> 6;
    int cg = lane & 3, qg = lane >> 2;
    int qrow = blockIdx.x*64 + wav*16 + qg;        // grid.x = 16
    int sh = blockIdx.y, split = blockIdx.z;
    int h = sh & (HEADS-1);
    const float* qp = qm + ((size_t)sh*NN + qrow)*CH + cg*12;
    float q0[12];
    {
        float4 t0=*(const float4*)qp, t1=*(const float4*)(qp+4), t2=*(const float4*)(qp+8);
        q0[0]=t0.x;q0[1]=t0.y;q0[2]=t0.z;q0[3]=t0.w;
        q0[4]=t1.x;q0[5]=t1.y;q0[6]=t1.z;q0[7]=t1.w;
        q0[8]=t2.x;q0[9]=t2.y;q0[10]=t2.z;q0[11]=t2.w;
    }
    float o[12];
    #pragma unroll
    for (int i=0;i<12;i++) o[i]=0.f;
    float m = -1e30f, l = 0.f;
    int k0 = split*(NN/KSPLIT);
    const float* pbrow = pb + ((size_t)h<<20) + (size_t)qrow*NN + k0;
    const float* kbase = km + ((size_t)sh*NN + k0)*CH + cg*12;
    const float* vbase = vm + ((size_t)sh*NN + k0)*CH + cg*12;
    for (int kc=0; kc<NN/KSPLIT; kc+=KCH){
        float sc[KCH];
        #pragma unroll
        for (int j=0;j<KCH;j++){
            const float4* kr = (const float4*)(kbase + (size_t)(kc+j)*CH);
            float4 ka=kr[0], kb4=kr[1], kc4=kr[2];
            float p = q0[0]*ka.x + q0[1]*ka.y + q0[2]*ka.z + q0[3]*ka.w
                    + q0[4]*kb4.x + q0[5]*kb4.y + q0[6]*kb4.z + q0[7]*kb4.w
                    + q0[8]*kc4.x + q0[9]*kc4.y + q0[10]*kc4.z + q0[11]*kc4.w;
            p += __shfl_xor(p, 1, 64);
            p += __shfl_xor(p, 2, 64);
            sc[j] = p + pbrow[kc+j];
        }
        float mc = m;
        #pragma unroll
        for (int j=0;j<KCH;j++) mc = fmaxf(mc, sc[j]);
        float corr = __expf(m - mc);
        m = mc;
        l *= corr;
        #pragma unroll
        for (int i=0;i<12;i++) o[i]*=corr;
        #pragma unroll
        for (int j=0;j<KCH;j++){
            float p = __expf(sc[j]-mc);
            l += p;
            const float4* vr = (const float4*)(vbase + (size_t)(kc+j)*CH);
            float4 va=vr[0], vb4=vr[1], vc4=vr[2];
            o[0]+=p*va.x;  o[1]+=p*va.y;  o[2]+=p*va.z;  o[3]+=p*va.w;
            o[4]+=p*vb4.x; o[5]+=p*vb4.y; o[6]+=p*vb4.z; o[7]+=p*vb4.w;
            o[8]+=p*vc4.x; o[9]+=p*vc4.y; o[10]+=p*vc4.z; o[11]+=p*vc4.w;
        }
    }
    size_t idx = (size_t)split*32768 + (size_t)sh*NN + qrow;
    if (cg==0){ pm[idx]=m; pl[idx]=l; }
    float* pop = po + idx*CH + cg*12;
    ((float4*)pop)[0]=make_float4(o[0],o[1],o[2],o[3]);
    ((float4*)pop)[1]=make_float4(o[4],o[5],o[6],o[7]);
    ((float4*)pop)[2]=make_float4(o[8],o[9],o[10],o[11]);
}

// combine k-splits, normalize, apply sigmoid gate, write o_g [2048,768]
__global__ __launch_bounds__(256) void k_combine(
    const float* __restrict__ pm, const float* __restrict__ pl,
    const float* __restrict__ po, const float* __restrict__ g,
    float* __restrict__ og)
{
    int gid = blockIdx.x*256+threadIdx.x;   // 32768*48 threads
    int row = gid / CH;                      // sh*N + qn
    int c = gid - row*CH;
    float mm = -1e30f;
    #pragma unroll
    for (int s=0;s<KSPLIT;s++) mm = fmaxf(mm, pm[s*32768+row]);
    float ls=0.f, os=0.f;
    #pragma unroll
    for (int s=0;s<KSPLIT;s++){
        float e = __expf(pm[s*32768+row]-mm);
        ls += pl[s*32768+row]*e;
        os += po[((size_t)s*32768+row)*CH + c]*e;
    }
    float oval = os/ls;
    int sh = row>>10; int qn = row & (NN-1);
    int s2 = sh>>4;   int hh = sh & 15;
    size_t orow = ((size_t)(s2*NN+qn))*DIMM + (size_t)hh*CH + c;
    og[orow] = oval * g[orow];
}

// ---------------------------------------------------------------------------
extern "C" void kernel_launch(void* const* d_in, const int* in_sizes, int n_in,
                              void* d_out, int out_size, void* d_ws, size_t ws_size,
                              hipStream_t stream)
{
    const float* srep   = (const float*)d_in[0];
    const float* sproj  = (const float*)d_in[1];
    const float* pair   = (const float*)d_in[2];
    const float* mask   = (const float*)d_in[3];
    const float* s_w    = (const float*)d_in[4];
    const float* gate_w = (const float*)d_in[5];
    const float* gate_b = (const float*)d_in[6];
    const float* skip_w = (const float*)d_in[7];
    const float* wq     = (const float*)d_in[8];
    const float* wk     = (const float*)d_in[9];
    const float* wv     = (const float*)d_in[10];
    const float* w_gate = (const float*)d_in[11];
    const float* b_gate = (const float*)d_in[12];
    const float* wo     = (const float*)d_in[13];
    const float* bo     = (const float*)d_in[14];
    const float* plnw   = (const float*)d_in[15];
    const float* plnb   = (const float*)d_in[16];
    const float* w_pair = (const float*)d_in[17];
    const float* w_out  = (const float*)d_in[18];
    const float* b_out  = (const float*)d_in[19];
    float* out = (float*)d_out;

    const size_t T = (size_t)NROWS*DIMM;   // 1572864
    float* w = (float*)d_ws;
    float* a_ln = w;                  // region0: a_ln,s_ln,(spare),a — aliased by po later
    float* s_ln = a_ln + T;
    float* spare= s_ln + T;           // kept for alias-size parity
    float* a    = spare + T;
    float* g    = w + 4*T;
    float* qb   = g + T;
    float* kb   = qb + T;
    float* vb   = kb + T;
    float* og   = vb + T;
    float* o2   = og + T;
    float* pbias= o2 + T;             // 16,777,216
    float* wpc  = pbias + (size_t)HEADS*NN*NN;
    float* csb  = wpc + 2048;         // 32
    float* pm   = csb + 32;           // KSPLIT*32768
    float* pl   = pm + KSPLIT*32768;
    float* po   = a_ln;               // alias: region0 dead before attention; 4*T == KSPLIT*32768*48

    k_ln_single<<<NROWS, 256, 0, stream>>>(srep, sproj, s_w, a_ln, s_ln);
    k_pair_pre<<<1, 256, 0, stream>>>(plnw, plnb, w_pair, wpc, csb);
    k_pair_bias<<<(NN*NN)/256, 256, 0, stream>>>(pair, wpc, csb, mask, pbias);

    k_adaln<<<dim3(NROWS/256, DIMM/8), 256, 0, stream>>>(s_ln, gate_w, skip_w, gate_b, a_ln, a);
    k_qkvg<<<dim3(NROWS/256, DIMM/16, 2), 256, 0, stream>>>(
        a, wq, wk, wv, w_gate, b_gate, qb, kb, vb, g);

    k_attn<<<dim3(NN/64, 2*HEADS, KSPLIT), 256, 0, stream>>>(qb, kb, vb, pbias, pm, pl, po);
    k_combine<<<(32768*CH)/256, 256, 0, stream>>>(pm, pl, po, g, og);

    k_gemm_wo<<<dim3(NROWS/256, DIMM/8), 256, 0, stream>>>(og, wo, bo, o2);
    k_gemm_out<<<dim3(NROWS/256, DIMM/8), 256, 0, stream>>>(o2, w_out, b_out, out);
}

// Round 3
// 863.534 us; speedup vs baseline: 1.6603x; 1.6603x over previous
//
#include <hip/hip_runtime.h>

#define NROWS 2048      // S*N rows
#define NN    1024
#define DIMM  768
#define HEADS 16
#define CH    48
#define CPAIR 128
#define KSPLIT 8
#define KCH   16

typedef unsigned short u16;
typedef unsigned int   u32;
typedef __attribute__((ext_vector_type(8))) short short8;
typedef __attribute__((ext_vector_type(4))) float f32x4;

__device__ __forceinline__ float sigm(float x){ return 1.0f/(1.0f+__expf(-x)); }
__device__ __forceinline__ u16 f2bf(float x){
    u32 u = __float_as_uint(x);
    u32 r = u + 0x7FFFu + ((u>>16)&1u);
    return (u16)(r>>16);
}
__device__ __forceinline__ float bf2f(u16 h){ return __uint_as_float(((u32)h)<<16); }
__device__ __forceinline__ void bfsplit(float x, u16& hi, u16& lo){
    hi = f2bf(x);
    lo = f2bf(x - bf2f(hi));
}

// ---------------------------------------------------------------------------
// LN of single_repr (no affine) -> a_ln f32;  LN(single_proj)*sw -> s hi/lo bf16
// ---------------------------------------------------------------------------
__global__ __launch_bounds__(256) void k_ln_single(
    const float* __restrict__ srep, const float* __restrict__ sproj,
    const float* __restrict__ sw, float* __restrict__ a_ln,
    u16* __restrict__ shi, u16* __restrict__ slo)
{
    int r = blockIdx.x, t = threadIdx.x;
    const float* xa = srep  + (size_t)r*DIMM;
    const float* xs = sproj + (size_t)r*DIMM;
    float va[3], vs[3];
    float sa=0.f,qa=0.f,ss=0.f,qs=0.f;
    #pragma unroll
    for (int i=0;i<3;i++){ float x=xa[t+256*i]; va[i]=x; sa+=x; qa+=x*x; }
    #pragma unroll
    for (int i=0;i<3;i++){ float x=xs[t+256*i]; vs[i]=x; ss+=x; qs+=x*x; }
    #pragma unroll
    for (int off=32; off>=1; off>>=1){
        sa += __shfl_xor(sa,off); qa += __shfl_xor(qa,off);
        ss += __shfl_xor(ss,off); qs += __shfl_xor(qs,off);
    }
    __shared__ float red[16];
    int w = t>>6;
    if ((t&63)==0){ red[w*4+0]=sa; red[w*4+1]=qa; red[w*4+2]=ss; red[w*4+3]=qs; }
    __syncthreads();
    sa = red[0]+red[4]+red[8]+red[12];
    qa = red[1]+red[5]+red[9]+red[13];
    ss = red[2]+red[6]+red[10]+red[14];
    qs = red[3]+red[7]+red[11]+red[15];
    float mua=sa*(1.f/768.f), mus=ss*(1.f/768.f);
    float rva=rsqrtf(fmaxf(qa*(1.f/768.f)-mua*mua,0.f)+1e-5f);
    float rvs=rsqrtf(fmaxf(qs*(1.f/768.f)-mus*mus,0.f)+1e-5f);
    #pragma unroll
    for (int i=0;i<3;i++){
        int c=t+256*i;
        size_t idx=(size_t)r*DIMM+c;
        a_ln[idx]=(va[i]-mua)*rva;
        float sv=(vs[i]-mus)*rvs*sw[c];
        u16 h,l; bfsplit(sv,h,l);
        shi[idx]=h; slo[idx]=l;
    }
}

// ---------------------------------------------------------------------------
// weight transpose + bf16 split: wT_hi/lo [n][k] from w [k][n], 8 weights
// ---------------------------------------------------------------------------
__global__ __launch_bounds__(256) void k_wsplit(
    const float* __restrict__ w0, const float* __restrict__ w1,
    const float* __restrict__ w2, const float* __restrict__ w3,
    const float* __restrict__ w4, const float* __restrict__ w5,
    const float* __restrict__ w6, const float* __restrict__ w7,
    u16* __restrict__ wt)
{
    __shared__ float tile[64][68];
    int n0 = blockIdx.x*64, k0 = blockIdx.y*64, z = blockIdx.z;
    const float* src;
    switch(z){
        case 0: src=w0; break; case 1: src=w1; break;
        case 2: src=w2; break; case 3: src=w3; break;
        case 4: src=w4; break; case 5: src=w5; break;
        case 6: src=w6; break; default: src=w7; break;
    }
    int t = threadIdx.x;
    #pragma unroll
    for (int it=0; it<4; it++){
        int idx = t + it*256;
        int kr = idx>>4, nc = (idx&15)*4;
        float4 v = *(const float4*)(src + (size_t)(k0+kr)*DIMM + n0+nc);
        *(float4*)(&tile[kr][nc]) = v;
    }
    __syncthreads();
    u16* wth = wt + (size_t)z*2*589824;
    u16* wtl = wth + 589824;
    #pragma unroll
    for (int it=0; it<4; it++){
        int idx = t + it*256;
        int nr = idx>>4, kc = (idx&15)*4;
        ushort4 h4, l4;
        u16 h,l;
        bfsplit(tile[kc+0][nr],h,l); h4.x=h; l4.x=l;
        bfsplit(tile[kc+1][nr],h,l); h4.y=h; l4.y=l;
        bfsplit(tile[kc+2][nr],h,l); h4.z=h; l4.z=l;
        bfsplit(tile[kc+3][nr],h,l); h4.w=h; l4.w=l;
        size_t o = (size_t)(n0+nr)*DIMM + k0+kc;
        *(ushort4*)(wth + o) = h4;
        *(ushort4*)(wtl + o) = l4;
    }
}

// ---------------------------------------------------------------------------
// pair bias precompute
// ---------------------------------------------------------------------------
__global__ void k_pair_pre(const float* __restrict__ lnw, const float* __restrict__ lnb,
                           const float* __restrict__ wp, float* __restrict__ wpc,
                           float* __restrict__ csb)
{
    int t = threadIdx.x;
    for (int i=t;i<2048;i+=256) wpc[i] = lnw[i>>4]*wp[i];
    if (t<16){
        float cs=0.f,b0=0.f;
        for (int c=0;c<128;c++){ cs += lnw[c]*wp[c*16+t]; b0 += lnb[c]*wp[c*16+t]; }
        csb[t]=cs; csb[16+t]=b0;
    }
}

// ---------------------------------------------------------------------------
// pair bias -> bf16: pb[h][i][j] = LN(pair[i,j,:]) @ w_pair[:,h] + INF*(mask[j]-1)
// ---------------------------------------------------------------------------
__global__ __launch_bounds__(256) void k_pair_bias(
    const float* __restrict__ pair, const float* __restrict__ wpc,
    const float* __restrict__ csb, const float* __restrict__ mask,
    u16* __restrict__ pb)
{
    int row = blockIdx.x*256 + threadIdx.x;
    int j = row & (NN-1);
    const float* x = pair + (size_t)row*CPAIR;
    float y[128];
    float s=0.f, q=0.f;
    #pragma unroll
    for (int c4=0;c4<32;c4++){
        float4 v = *(const float4*)(x + 4*c4);
        y[4*c4]=v.x; y[4*c4+1]=v.y; y[4*c4+2]=v.z; y[4*c4+3]=v.w;
        s += v.x+v.y+v.z+v.w;
        q += v.x*v.x+v.y*v.y+v.z*v.z+v.w*v.w;
    }
    float mu = s*(1.f/128.f);
    float rs = rsqrtf(fmaxf(q*(1.f/128.f)-mu*mu,0.f)+1e-5f);
    float acc[16];
    #pragma unroll
    for (int h=0;h<16;h++) acc[h]=0.f;
    #pragma unroll
    for (int c=0;c<128;c++){
        float yc = y[c];
        const float4* wr = (const float4*)(wpc + c*16);
        float4 w0=wr[0], w1=wr[1], w2=wr[2], w3=wr[3];
        acc[0]+=yc*w0.x; acc[1]+=yc*w0.y; acc[2]+=yc*w0.z; acc[3]+=yc*w0.w;
        acc[4]+=yc*w1.x; acc[5]+=yc*w1.y; acc[6]+=yc*w1.z; acc[7]+=yc*w1.w;
        acc[8]+=yc*w2.x; acc[9]+=yc*w2.y; acc[10]+=yc*w2.z; acc[11]+=yc*w2.w;
        acc[12]+=yc*w3.x; acc[13]+=yc*w3.y; acc[14]+=yc*w3.z; acc[15]+=yc*w3.w;
    }
    float mb = 1e8f*(mask[j]-1.f);
    #pragma unroll
    for (int h=0;h<16;h++){
        float out = (acc[h]-mu*csb[h])*rs + csb[16+h] + mb;
        pb[((size_t)h<<20) + row] = f2bf(out);
    }
}

// ---------------------------------------------------------------------------
// bf16x2-split MFMA GEMM: C[2048,768] = A[2048,768] @ B[768,768]
// A planes [m][k]; B planes TRANSPOSED [n][k]. Tile 64x64, BK=32, 4 waves.
// NB = number of B matrices sharing the A pass. EPI selects epilogue.
// ---------------------------------------------------------------------------
template<int NB, int EPI>
__global__ __launch_bounds__(256) void k_gemm(
    const u16* __restrict__ Ahp, const u16* __restrict__ Alp,
    const u16* __restrict__ B0h, const u16* __restrict__ B0l,
    const u16* __restrict__ B1h, const u16* __restrict__ B1l,
    const float* __restrict__ e0, const float* __restrict__ e1,
    float* __restrict__ o0, float* __restrict__ o1,
    u16* __restrict__ oh, u16* __restrict__ ol)
{
    __shared__ u16 lAh[64][40], lAl[64][40];
    __shared__ u16 lBh[NB][64][40], lBl[NB][64][40];
    int m0 = blockIdx.x*64, n0 = blockIdx.y*64;
    int t = threadIdx.x, lane = t&63, w = t>>6;
    int srow = t>>2, sk8 = (t&3)*8;
    int fr = lane&15, fg = lane>>4;
    f32x4 acc[NB][4];
    #pragma unroll
    for (int i=0;i<NB;i++)
        #pragma unroll
        for (int nf=0;nf<4;nf++) acc[i][nf] = (f32x4){0.f,0.f,0.f,0.f};

    for (int k0=0; k0<DIMM; k0+=32){
        size_t ga = (size_t)(m0+srow)*DIMM + k0 + sk8;
        int4 va = *(const int4*)(Ahp + ga);
        int4 vb = *(const int4*)(Alp + ga);
        *(int4*)(&lAh[srow][sk8]) = va;
        *(int4*)(&lAl[srow][sk8]) = vb;
        size_t gb = (size_t)(n0+srow)*DIMM + k0 + sk8;
        {
            int4 b0 = *(const int4*)(B0h + gb);
            int4 b1 = *(const int4*)(B0l + gb);
            *(int4*)(&lBh[0][srow][sk8]) = b0;
            *(int4*)(&lBl[0][srow][sk8]) = b1;
        }
        if (NB==2){
            int4 b0 = *(const int4*)(B1h + gb);
            int4 b1 = *(const int4*)(B1l + gb);
            *(int4*)(&lBh[1][srow][sk8]) = b0;
            *(int4*)(&lBl[1][srow][sk8]) = b1;
        }
        __syncthreads();
        short8 a_h = *(const short8*)(&lAh[w*16 + fr][fg*8]);
        short8 a_l = *(const short8*)(&lAl[w*16 + fr][fg*8]);
        #pragma unroll
        for (int nf=0;nf<4;nf++){
            #pragma unroll
            for (int i=0;i<NB;i++){
                short8 b_h = *(const short8*)(&lBh[i][nf*16 + fr][fg*8]);
                short8 b_l = *(const short8*)(&lBl[i][nf*16 + fr][fg*8]);
                acc[i][nf] = __builtin_amdgcn_mfma_f32_16x16x32_bf16(a_h, b_h, acc[i][nf], 0,0,0);
                acc[i][nf] = __builtin_amdgcn_mfma_f32_16x16x32_bf16(a_h, b_l, acc[i][nf], 0,0,0);
                acc[i][nf] = __builtin_amdgcn_mfma_f32_16x16x32_bf16(a_l, b_h, acc[i][nf], 0,0,0);
            }
        }
        __syncthreads();
    }
    // epilogue: D mapping col=lane&15, row=fg*4+reg (per 16x16 frag)
    #pragma unroll
    for (int nf=0;nf<4;nf++){
        #pragma unroll
        for (int r=0;r<4;r++){
            int row = m0 + w*16 + fg*4 + r;
            int col = n0 + nf*16 + fr;
            size_t idx = (size_t)row*DIMM + col;
            float c0 = acc[0][nf][r];
            if (EPI==0){           // adaln: sigm(c0+gb)*a_ln + c1 -> split
                float c1 = acc[1][nf][r];
                float v = sigm(c0 + e0[col]) * e1[idx] + c1;
                u16 h,l; bfsplit(v,h,l); oh[idx]=h; ol[idx]=l;
            } else if (EPI==1){    // q (scaled), k  -> f32
                float c1 = acc[1][nf][r];
                o0[idx] = c0 * 0.14433756729740643f;
                o1[idx] = c1;
            } else if (EPI==2){    // v, gate=sigm(c1+b_gate) -> f32
                float c1 = acc[1][nf][r];
                o0[idx] = c0;
                o1[idx] = sigm(c1 + e0[col]);
            } else if (EPI==3){    // o2 = c0 + bo -> split
                float v = c0 + e0[col];
                u16 h,l; bfsplit(v,h,l); oh[idx]=h; ol[idx]=l;
            } else {               // EPI==4: out = sigm(c0 + b_out) * o2
                float o2v = bf2f(Ahp[idx]) + bf2f(Alp[idx]);
                o0[idx] = sigm(c0 + e0[col]) * o2v;
            }
        }
    }
}

// ---------------------------------------------------------------------------
// flash attention: lane = q-row (R1 structure), KSPLIT=8 k-ranges.
// q/k/v f32 [2048,768]; pbias bf16; po partials bf16.
// ---------------------------------------------------------------------------
__global__ __launch_bounds__(256) void k_attn(
    const float* __restrict__ qm, const float* __restrict__ km,
    const float* __restrict__ vm, const u16* __restrict__ pb,
    float* __restrict__ pm, float* __restrict__ pl, u16* __restrict__ po)
{
    int qrow = blockIdx.x*256 + threadIdx.x;       // grid.x = 4
    int sh = blockIdx.y, split = blockIdx.z;
    int s = sh>>4, h = sh & (HEADS-1);
    const float* qp = qm + ((size_t)(s*NN + qrow))*DIMM + h*CH;
    float4 qv[12];
    #pragma unroll
    for (int i=0;i<12;i++) qv[i] = *(const float4*)(qp + 4*i);
    float4 o[12];
    #pragma unroll
    for (int i=0;i<12;i++) o[i] = make_float4(0.f,0.f,0.f,0.f);
    float m = -1e30f, l = 0.f;
    int k0 = split*(NN/KSPLIT);
    const u16* pbrow = pb + ((size_t)h<<20) + (size_t)qrow*NN + k0;
    const float* kbase = km + ((size_t)(s*NN + k0))*DIMM + h*CH;
    const float* vbase = vm + ((size_t)(s*NN + k0))*DIMM + h*CH;
    for (int kc=0; kc<NN/KSPLIT; kc+=KCH){
        float sc[KCH];
        #pragma unroll
        for (int j=0;j<KCH;j++){
            const float4* kr = (const float4*)(kbase + (size_t)(kc+j)*DIMM);
            float a0 = bf2f(pbrow[kc+j]);
            #pragma unroll
            for (int c=0;c<12;c++){
                float4 kv = kr[c];
                a0 += qv[c].x*kv.x + qv[c].y*kv.y + qv[c].z*kv.z + qv[c].w*kv.w;
            }
            sc[j]=a0;
        }
        float mc = m;
        #pragma unroll
        for (int j=0;j<KCH;j++) mc = fmaxf(mc, sc[j]);
        float corr = __expf(m - mc);
        m = mc;
        l *= corr;
        #pragma unroll
        for (int i=0;i<12;i++){ o[i].x*=corr; o[i].y*=corr; o[i].z*=corr; o[i].w*=corr; }
        #pragma unroll
        for (int j=0;j<KCH;j++){
            float p = __expf(sc[j]-mc);
            l += p;
            const float4* vr = (const float4*)(vbase + (size_t)(kc+j)*DIMM);
            #pragma unroll
            for (int c=0;c<12;c++){
                float4 vv = vr[c];
                o[c].x+=p*vv.x; o[c].y+=p*vv.y; o[c].z+=p*vv.z; o[c].w+=p*vv.w;
            }
        }
    }
    size_t idx = (size_t)split*32768 + (size_t)sh*NN + qrow;
    pm[idx]=m; pl[idx]=l;
    u16* pop = po + idx*CH;
    #pragma unroll
    for (int i=0;i<12;i++){
        ushort4 pk;
        pk.x = f2bf(o[i].x); pk.y = f2bf(o[i].y);
        pk.z = f2bf(o[i].z); pk.w = f2bf(o[i].w);
        *(ushort4*)(pop + 4*i) = pk;
    }
}

// combine k-splits, normalize, gate, write og split planes [2048,768]
__global__ __launch_bounds__(256) void k_combine(
    const float* __restrict__ pm, const float* __restrict__ pl,
    const u16* __restrict__ po, const float* __restrict__ g,
    u16* __restrict__ oghi, u16* __restrict__ oglo)
{
    int gid = blockIdx.x*256+threadIdx.x;   // 32768*48 threads
    int row = gid / CH;                      // sh*N + qn
    int c = gid - row*CH;
    float mm = -1e30f;
    #pragma unroll
    for (int s=0;s<KSPLIT;s++) mm = fmaxf(mm, pm[s*32768+row]);
    float ls=0.f, os=0.f;
    #pragma unroll
    for (int s=0;s<KSPLIT;s++){
        float e = __expf(pm[s*32768+row]-mm);
        ls += pl[s*32768+row]*e;
        os += bf2f(po[((size_t)s*32768+row)*CH + c])*e;
    }
    float oval = os/ls;
    int sh = row>>10; int qn = row & (NN-1);
    int s2 = sh>>4;   int hh = sh & 15;
    size_t orow = ((size_t)(s2*NN+qn))*DIMM + (size_t)hh*CH + c;
    float v = oval * g[orow];
    u16 h,l; bfsplit(v,h,l);
    oghi[orow]=h; oglo[orow]=l;
}

// ---------------------------------------------------------------------------
extern "C" void kernel_launch(void* const* d_in, const int* in_sizes, int n_in,
                              void* d_out, int out_size, void* d_ws, size_t ws_size,
                              hipStream_t stream)
{
    const float* srep   = (const float*)d_in[0];
    const float* sproj  = (const float*)d_in[1];
    const float* pair   = (const float*)d_in[2];
    const float* mask   = (const float*)d_in[3];
    const float* s_w    = (const float*)d_in[4];
    const float* gate_w = (const float*)d_in[5];
    const float* gate_b = (const float*)d_in[6];
    const float* skip_w = (const float*)d_in[7];
    const float* wq     = (const float*)d_in[8];
    const float* wk     = (const float*)d_in[9];
    const float* wv     = (const float*)d_in[10];
    const float* w_gate = (const float*)d_in[11];
    const float* b_gate = (const float*)d_in[12];
    const float* wo     = (const float*)d_in[13];
    const float* bo     = (const float*)d_in[14];
    const float* plnw   = (const float*)d_in[15];
    const float* plnb   = (const float*)d_in[16];
    const float* w_pair = (const float*)d_in[17];
    const float* w_out  = (const float*)d_in[18];
    const float* b_out  = (const float*)d_in[19];
    float* out = (float*)d_out;

    const size_t T  = (size_t)NROWS*DIMM;       // 1,572,864
    const size_t W  = (size_t)DIMM*DIMM;        // 589,824
    const size_t PM = (size_t)KSPLIT*32768;     // 262,144
    const size_t PB = (size_t)HEADS*NN*NN;      // 16,777,216

    char* p = (char*)d_ws;
    float* a_ln = (float*)p; p += T*4;
    float* q    = (float*)p; p += T*4;
    float* k    = (float*)p; p += T*4;
    float* v    = (float*)p; p += T*4;
    float* g    = (float*)p; p += T*4;
    float* wpc  = (float*)p; p += 2048*4;
    float* csb  = (float*)p; p += 32*4;
    float* pm   = (float*)p; p += PM*4;
    float* pl   = (float*)p; p += PM*4;
    u16* shi  = (u16*)p; p += T*2;
    u16* slo  = (u16*)p; p += T*2;
    u16* ahi  = (u16*)p; p += T*2;
    u16* alo  = (u16*)p; p += T*2;
    u16* oghi = (u16*)p; p += T*2;
    u16* oglo = (u16*)p; p += T*2;
    u16* o2hi = (u16*)p; p += T*2;
    u16* o2lo = (u16*)p; p += T*2;
    u16* pb   = (u16*)p; p += PB*2;
    u16* wt   = (u16*)p; p += 16*W*2;
    u16* po   = (u16*)p; p += PM*CH*2;

    // weight plane helpers: index i -> hi = wt + i*2*W, lo = hi + W
    #define WH(i) (wt + (size_t)(i)*2*W)
    #define WL(i) (wt + (size_t)(i)*2*W + W)

    k_wsplit<<<dim3(12,12,8), 256, 0, stream>>>(
        gate_w, skip_w, wq, wk, wv, w_gate, wo, w_out, wt);
    k_ln_single<<<NROWS, 256, 0, stream>>>(srep, sproj, s_w, a_ln, shi, slo);
    k_pair_pre<<<1, 256, 0, stream>>>(plnw, plnb, w_pair, wpc, csb);
    k_pair_bias<<<(NN*NN)/256, 256, 0, stream>>>(pair, wpc, csb, mask, pb);

    dim3 gg(NROWS/64, DIMM/64);
    // G1: a = sigm(s@gate_w + gate_b)*a_ln + s@skip_w  -> a planes
    k_gemm<2,0><<<gg, 256, 0, stream>>>(shi, slo, WH(0), WL(0), WH(1), WL(1),
                                        gate_b, a_ln, nullptr, nullptr, ahi, alo);
    // G2: q = (a@wq)*scale, k = a@wk
    k_gemm<2,1><<<gg, 256, 0, stream>>>(ahi, alo, WH(2), WL(2), WH(3), WL(3),
                                        nullptr, nullptr, q, k, nullptr, nullptr);
    // G3: v = a@wv, g = sigm(a@w_gate + b_gate)
    k_gemm<2,2><<<gg, 256, 0, stream>>>(ahi, alo, WH(4), WL(4), WH(5), WL(5),
                                        b_gate, nullptr, v, g, nullptr, nullptr);

    k_attn<<<dim3(NN/256, 2*HEADS, KSPLIT), 256, 0, stream>>>(q, k, v, pb, pm, pl, po);
    k_combine<<<(32768*CH)/256, 256, 0, stream>>>(pm, pl, po, g, oghi, oglo);

    // G4: o2 = og@wo + bo -> o2 planes
    k_gemm<1,3><<<gg, 256, 0, stream>>>(oghi, oglo, WH(6), WL(6), nullptr, nullptr,
                                        bo, nullptr, nullptr, nullptr, o2hi, o2lo);
    // G5: out = sigm(o2@w_out + b_out) * o2
    k_gemm<1,4><<<gg, 256, 0, stream>>>(o2hi, o2lo, WH(7), WL(7), nullptr, nullptr,
                                        b_out, nullptr, out, nullptr, nullptr, nullptr);
    #undef WH
    #undef WL
}

// Round 6
// 597.701 us; speedup vs baseline: 2.3987x; 1.4448x over previous
//
#include <hip/hip_runtime.h>

#define NROWS 2048      // S*N rows
#define NN    1024
#define DIMM  768
#define HEADS 16
#define CH    48
#define CPAIR 128

typedef unsigned short u16;
typedef unsigned int   u32;
typedef __attribute__((ext_vector_type(8))) short short8;
typedef __attribute__((ext_vector_type(4))) float f32x4;

__device__ __forceinline__ float sigm(float x){ return 1.0f/(1.0f+__expf(-x)); }
__device__ __forceinline__ u16 f2bf(float x){
    u32 u = __float_as_uint(x);
    u32 r = u + 0x7FFFu + ((u>>16)&1u);
    return (u16)(r>>16);
}
__device__ __forceinline__ float bf2f(u16 h){ return __uint_as_float(((u32)h)<<16); }
__device__ __forceinline__ void bfsplit(float x, u16& hi, u16& lo){
    hi = f2bf(x);
    lo = f2bf(x - bf2f(hi));
}

// ---------------------------------------------------------------------------
// LN of single_repr (no affine) -> a_ln f32;  LN(single_proj)*sw -> s hi/lo bf16
// ---------------------------------------------------------------------------
__global__ __launch_bounds__(256) void k_ln_single(
    const float* __restrict__ srep, const float* __restrict__ sproj,
    const float* __restrict__ sw, float* __restrict__ a_ln,
    u16* __restrict__ shi, u16* __restrict__ slo)
{
    int r = blockIdx.x, t = threadIdx.x;
    const float* xa = srep  + (size_t)r*DIMM;
    const float* xs = sproj + (size_t)r*DIMM;
    float va[3], vs[3];
    float sa=0.f,qa=0.f,ss=0.f,qs=0.f;
    #pragma unroll
    for (int i=0;i<3;i++){ float x=xa[t+256*i]; va[i]=x; sa+=x; qa+=x*x; }
    #pragma unroll
    for (int i=0;i<3;i++){ float x=xs[t+256*i]; vs[i]=x; ss+=x; qs+=x*x; }
    #pragma unroll
    for (int off=32; off>=1; off>>=1){
        sa += __shfl_xor(sa,off); qa += __shfl_xor(qa,off);
        ss += __shfl_xor(ss,off); qs += __shfl_xor(qs,off);
    }
    __shared__ float red[16];
    int w = t>>6;
    if ((t&63)==0){ red[w*4+0]=sa; red[w*4+1]=qa; red[w*4+2]=ss; red[w*4+3]=qs; }
    __syncthreads();
    sa = red[0]+red[4]+red[8]+red[12];
    qa = red[1]+red[5]+red[9]+red[13];
    ss = red[2]+red[6]+red[10]+red[14];
    qs = red[3]+red[7]+red[11]+red[15];
    float mua=sa*(1.f/768.f), mus=ss*(1.f/768.f);
    float rva=rsqrtf(fmaxf(qa*(1.f/768.f)-mua*mua,0.f)+1e-5f);
    float rvs=rsqrtf(fmaxf(qs*(1.f/768.f)-mus*mus,0.f)+1e-5f);
    #pragma unroll
    for (int i=0;i<3;i++){
        int c=t+256*i;
        size_t idx=(size_t)r*DIMM+c;
        a_ln[idx]=(va[i]-mua)*rva;
        float sv=(vs[i]-mus)*rvs*sw[c];
        u16 h,l; bfsplit(sv,h,l);
        shi[idx]=h; slo[idx]=l;
    }
}

// ---------------------------------------------------------------------------
// weight transpose + bf16 split: wT_hi/lo [n][k] from w [k][n], 8 weights
// ---------------------------------------------------------------------------
__global__ __launch_bounds__(256) void k_wsplit(
    const float* __restrict__ w0, const float* __restrict__ w1,
    const float* __restrict__ w2, const float* __restrict__ w3,
    const float* __restrict__ w4, const float* __restrict__ w5,
    const float* __restrict__ w6, const float* __restrict__ w7,
    u16* __restrict__ wt)
{
    __shared__ float tile[64][68];
    int n0 = blockIdx.x*64, k0 = blockIdx.y*64, z = blockIdx.z;
    const float* src;
    switch(z){
        case 0: src=w0; break; case 1: src=w1; break;
        case 2: src=w2; break; case 3: src=w3; break;
        case 4: src=w4; break; case 5: src=w5; break;
        case 6: src=w6; break; default: src=w7; break;
    }
    int t = threadIdx.x;
    #pragma unroll
    for (int it=0; it<4; it++){
        int idx = t + it*256;
        int kr = idx>>4, nc = (idx&15)*4;
        float4 v = *(const float4*)(src + (size_t)(k0+kr)*DIMM + n0+nc);
        *(float4*)(&tile[kr][nc]) = v;
    }
    __syncthreads();
    u16* wth = wt + (size_t)z*2*589824;
    u16* wtl = wth + 589824;
    #pragma unroll
    for (int it=0; it<4; it++){
        int idx = t + it*256;
        int nr = idx>>4, kc = (idx&15)*4;
        ushort4 h4, l4;
        u16 h,l;
        bfsplit(tile[kc+0][nr],h,l); h4.x=h; l4.x=l;
        bfsplit(tile[kc+1][nr],h,l); h4.y=h; l4.y=l;
        bfsplit(tile[kc+2][nr],h,l); h4.z=h; l4.z=l;
        bfsplit(tile[kc+3][nr],h,l); h4.w=h; l4.w=l;
        size_t o = (size_t)(n0+nr)*DIMM + k0+kc;
        *(ushort4*)(wth + o) = h4;
        *(ushort4*)(wtl + o) = l4;
    }
}

// ---------------------------------------------------------------------------
// pair bias precompute
// ---------------------------------------------------------------------------
__global__ void k_pair_pre(const float* __restrict__ lnw, const float* __restrict__ lnb,
                           const float* __restrict__ wp, float* __restrict__ wpc,
                           float* __restrict__ csb)
{
    int t = threadIdx.x;
    for (int i=t;i<2048;i+=256) wpc[i] = lnw[i>>4]*wp[i];
    if (t<16){
        float cs=0.f,b0=0.f;
        for (int c=0;c<128;c++){ cs += lnw[c]*wp[c*16+t]; b0 += lnb[c]*wp[c*16+t]; }
        csb[t]=cs; csb[16+t]=b0;
    }
}

// ---------------------------------------------------------------------------
// pair bias -> bf16: pb[h][i][j] = LN(pair[i,j,:]) @ w_pair[:,h] + INF*(mask[j]-1)
// ---------------------------------------------------------------------------
__global__ __launch_bounds__(256) void k_pair_bias(
    const float* __restrict__ pair, const float* __restrict__ wpc,
    const float* __restrict__ csb, const float* __restrict__ mask,
    u16* __restrict__ pb)
{
    int row = blockIdx.x*256 + threadIdx.x;
    int j = row & (NN-1);
    const float* x = pair + (size_t)row*CPAIR;
    float y[128];
    float s=0.f, q=0.f;
    #pragma unroll
    for (int c4=0;c4<32;c4++){
        float4 v = *(const float4*)(x + 4*c4);
        y[4*c4]=v.x; y[4*c4+1]=v.y; y[4*c4+2]=v.z; y[4*c4+3]=v.w;
        s += v.x+v.y+v.z+v.w;
        q += v.x*v.x+v.y*v.y+v.z*v.z+v.w*v.w;
    }
    float mu = s*(1.f/128.f);
    float rs = rsqrtf(fmaxf(q*(1.f/128.f)-mu*mu,0.f)+1e-5f);
    float acc[16];
    #pragma unroll
    for (int h=0;h<16;h++) acc[h]=0.f;
    #pragma unroll
    for (int c=0;c<128;c++){
        float yc = y[c];
        const float4* wr = (const float4*)(wpc + c*16);
        float4 w0=wr[0], w1=wr[1], w2=wr[2], w3=wr[3];
        acc[0]+=yc*w0.x; acc[1]+=yc*w0.y; acc[2]+=yc*w0.z; acc[3]+=yc*w0.w;
        acc[4]+=yc*w1.x; acc[5]+=yc*w1.y; acc[6]+=yc*w1.z; acc[7]+=yc*w1.w;
        acc[8]+=yc*w2.x; acc[9]+=yc*w2.y; acc[10]+=yc*w2.z; acc[11]+=yc*w2.w;
        acc[12]+=yc*w3.x; acc[13]+=yc*w3.y; acc[14]+=yc*w3.z; acc[15]+=yc*w3.w;
    }
    float mb = 1e8f*(mask[j]-1.f);
    #pragma unroll
    for (int h=0;h<16;h++){
        float out = (acc[h]-mu*csb[h])*rs + csb[16+h] + mb;
        pb[((size_t)h<<20) + row] = f2bf(out);
    }
}

// ---------------------------------------------------------------------------
// bf16x2-split MFMA GEMM: C[2048,768] = A[2048,768] @ B[768,768]
// A planes [m][k]; B planes TRANSPOSED [n][k]. Tile 64x64, BK=32, 4 waves.
// ---------------------------------------------------------------------------
template<int NB, int EPI>
__global__ __launch_bounds__(256) void k_gemm(
    const u16* __restrict__ Ahp, const u16* __restrict__ Alp,
    const u16* __restrict__ B0h, const u16* __restrict__ B0l,
    const u16* __restrict__ B1h, const u16* __restrict__ B1l,
    const float* __restrict__ e0, const float* __restrict__ e1,
    float* __restrict__ o0, float* __restrict__ o1,
    u16* __restrict__ oh, u16* __restrict__ ol)
{
    __shared__ u16 lAh[64][40], lAl[64][40];
    __shared__ u16 lBh[NB][64][40], lBl[NB][64][40];
    int m0 = blockIdx.x*64, n0 = blockIdx.y*64;
    int t = threadIdx.x, lane = t&63, w = t>>6;
    int srow = t>>2, sk8 = (t&3)*8;
    int fr = lane&15, fg = lane>>4;
    f32x4 acc[NB][4];
    #pragma unroll
    for (int i=0;i<NB;i++)
        #pragma unroll
        for (int nf=0;nf<4;nf++) acc[i][nf] = (f32x4){0.f,0.f,0.f,0.f};

    for (int k0=0; k0<DIMM; k0+=32){
        size_t ga = (size_t)(m0+srow)*DIMM + k0 + sk8;
        int4 va = *(const int4*)(Ahp + ga);
        int4 vb = *(const int4*)(Alp + ga);
        *(int4*)(&lAh[srow][sk8]) = va;
        *(int4*)(&lAl[srow][sk8]) = vb;
        size_t gb = (size_t)(n0+srow)*DIMM + k0 + sk8;
        {
            int4 b0 = *(const int4*)(B0h + gb);
            int4 b1 = *(const int4*)(B0l + gb);
            *(int4*)(&lBh[0][srow][sk8]) = b0;
            *(int4*)(&lBl[0][srow][sk8]) = b1;
        }
        if (NB==2){
            int4 b0 = *(const int4*)(B1h + gb);
            int4 b1 = *(const int4*)(B1l + gb);
            *(int4*)(&lBh[1][srow][sk8]) = b0;
            *(int4*)(&lBl[1][srow][sk8]) = b1;
        }
        __syncthreads();
        short8 a_h = *(const short8*)(&lAh[w*16 + fr][fg*8]);
        short8 a_l = *(const short8*)(&lAl[w*16 + fr][fg*8]);
        #pragma unroll
        for (int nf=0;nf<4;nf++){
            #pragma unroll
            for (int i=0;i<NB;i++){
                short8 b_h = *(const short8*)(&lBh[i][nf*16 + fr][fg*8]);
                short8 b_l = *(const short8*)(&lBl[i][nf*16 + fr][fg*8]);
                acc[i][nf] = __builtin_amdgcn_mfma_f32_16x16x32_bf16(a_h, b_h, acc[i][nf], 0,0,0);
                acc[i][nf] = __builtin_amdgcn_mfma_f32_16x16x32_bf16(a_h, b_l, acc[i][nf], 0,0,0);
                acc[i][nf] = __builtin_amdgcn_mfma_f32_16x16x32_bf16(a_l, b_h, acc[i][nf], 0,0,0);
            }
        }
        __syncthreads();
    }
    // epilogue: D mapping col=lane&15, row=fg*4+reg (per 16x16 frag)
    #pragma unroll
    for (int nf=0;nf<4;nf++){
        #pragma unroll
        for (int r=0;r<4;r++){
            int row = m0 + w*16 + fg*4 + r;
            int col = n0 + nf*16 + fr;
            size_t idx = (size_t)row*DIMM + col;
            float c0 = acc[0][nf][r];
            if (EPI==0){           // adaln: sigm(c0+gb)*a_ln + c1 -> split planes
                float c1 = acc[1][nf][r];
                float v = sigm(c0 + e0[col]) * e1[idx] + c1;
                u16 h,l; bfsplit(v,h,l); oh[idx]=h; ol[idx]=l;
            } else if (EPI==1){    // q (scaled) -> oh/ol planes; k -> o0/o1 (cast u16)
                u16* kh_ = (u16*)o0; u16* kl_ = (u16*)o1;
                int s2 = row>>10, n = row&(NN-1);
                int hh2 = col/CH, cc = col-hh2*CH;   // 16-col frag never straddles a head
                size_t pidx = ((size_t)(s2*HEADS+hh2)*NN + n)*CH + cc;
                u16 hx,lx;
                bfsplit(c0*0.14433756729740643f, hx,lx);
                oh[pidx]=hx; ol[pidx]=lx;
                float c1 = acc[1][nf][r];
                bfsplit(c1,hx,lx);
                kh_[pidx]=hx; kl_[pidx]=lx;
            } else if (EPI==2){    // v -> transposed planes oh/ol; gate -> o0 f32
                int s2 = row>>10, n = row&(NN-1);
                int hh2 = col/CH, cc = col-hh2*CH;
                size_t vidx = ((size_t)(s2*HEADS+hh2)*CH + cc)*NN + n;
                u16 hx,lx; bfsplit(c0,hx,lx);
                oh[vidx]=hx; ol[vidx]=lx;
                float c1 = acc[1][nf][r];
                o0[idx] = sigm(c1 + e0[col]);
            } else if (EPI==3){    // o2 = c0 + bo -> split planes
                float v = c0 + e0[col];
                u16 h,l; bfsplit(v,h,l); oh[idx]=h; ol[idx]=l;
            } else {               // EPI==4: out = sigm(c0 + b_out) * o2
                float o2v = bf2f(Ahp[idx]) + bf2f(Alp[idx]);
                o0[idx] = sigm(c0 + e0[col]) * o2v;
            }
        }
    }
}

// ---------------------------------------------------------------------------
// flash attention on MFMA. block = 64 q-rows of one (s,h); 4 waves x 16 rows.
// q/k planes [s][h][n][48] hi/lo bf16 (q pre-scaled); v planes [s][h][c][n].
// Writes og split planes [token][768] = (O/l) * gate.
// ---------------------------------------------------------------------------
__global__ __launch_bounds__(256) void k_attn(
    const u16* __restrict__ qah, const u16* __restrict__ qal,
    const u16* __restrict__ kah, const u16* __restrict__ kal,
    const u16* __restrict__ vth, const u16* __restrict__ vtl,
    const u16* __restrict__ pb, const float* __restrict__ g,
    u16* __restrict__ oghi, u16* __restrict__ oglo)
{
    __shared__ u16 lQh[64][72], lQl[64][72], lKh[64][72], lKl[64][72];
    __shared__ u16 lVh[48][72], lVl[48][72];
    __shared__ u16 lP[4][16][72];
    int t = threadIdx.x, lane = t&63, w = t>>6;
    int fr = lane&15, fg = lane>>4;
    int m0 = blockIdx.x*64;
    int sh = blockIdx.y, s = sh>>4, h = sh&15;
    size_t qkbase = (size_t)sh*NN*CH;   // [s][h][n][48]
    size_t vbase  = (size_t)sh*CH*NN;   // [s][h][c][n]

    // zero K-pad cols 48..63 of Q/K tiles (once; stages never touch them)
    {
        int row = t>>2, which = t&3;
        u16* dst = (which==0)? &lQh[row][48] : (which==1)? &lQl[row][48] :
                   (which==2)? &lKh[row][48] : &lKl[row][48];
        *(int4*)dst     = make_int4(0,0,0,0);
        *(int4*)(dst+8) = make_int4(0,0,0,0);
    }
    // stage Q tile (64 rows x 48 u16, hi+lo = 768 16B-segs, 3 per thread)
    {
        const u16* src0 = qah + qkbase + (size_t)m0*CH;
        const u16* src1 = qal + qkbase + (size_t)m0*CH;
        #pragma unroll
        for (int it=0; it<3; it++){
            int sid = t + it*256;
            int plane = sid>=384; int s2 = plane ? sid-384 : sid;
            int row = s2/6, seg = s2-row*6;
            int4 v = *(const int4*)((plane?src1:src0) + row*CH + seg*8);
            u16 (*dq)[72] = plane? lQl : lQh;
            *(int4*)(&dq[row][seg*8]) = v;
        }
    }
    __syncthreads();
    short8 aqh0 = *(const short8*)(&lQh[w*16+fr][fg*8]);
    short8 aqh1 = *(const short8*)(&lQh[w*16+fr][32+fg*8]);
    short8 aql0 = *(const short8*)(&lQl[w*16+fr][fg*8]);
    short8 aql1 = *(const short8*)(&lQl[w*16+fr][32+fg*8]);

    f32x4 acc_o[3];
    #pragma unroll
    for (int i=0;i<3;i++) acc_o[i]=(f32x4){0.f,0.f,0.f,0.f};
    float m[4], l[4];
    #pragma unroll
    for (int r=0;r<4;r++){ m[r]=-3e38f; l[r]=0.f; }
    int qrow_base = m0 + w*16 + fg*4;
    const u16* pbq = pb + ((size_t)h<<20) + (size_t)qrow_base*NN + fr;

    for (int kt=0; kt<16; kt++){
        int k0 = kt*64;
        // global loads for K and V^T staging (regs), + pair-bias loads
        int4 kreg[3], vreg[3];
        const u16* ksrc0 = kah + qkbase + (size_t)k0*CH;
        const u16* ksrc1 = kal + qkbase + (size_t)k0*CH;
        const u16* vsrc0 = vth + vbase + k0;
        const u16* vsrc1 = vtl + vbase + k0;
        #pragma unroll
        for (int it=0; it<3; it++){
            int sid = t + it*256;
            int plane = sid>=384; int s2 = plane ? sid-384 : sid;
            int row = s2/6, seg = s2-row*6;
            kreg[it] = *(const int4*)((plane?ksrc1:ksrc0) + row*CH + seg*8);
            int rowv = s2>>3, segv = s2&7;
            vreg[it] = *(const int4*)((plane?vsrc1:vsrc0) + (size_t)rowv*NN + segv*8);
        }
        u16 pbv[4][4];
        #pragma unroll
        for (int r=0;r<4;r++)
            #pragma unroll
            for (int nf=0;nf<4;nf++)
                pbv[r][nf] = pbq[(size_t)r*NN + k0 + nf*16];
        __syncthreads();   // previous iteration's LDS reads complete
        #pragma unroll
        for (int it=0; it<3; it++){
            int sid = t + it*256;
            int plane = sid>=384; int s2 = plane ? sid-384 : sid;
            int row = s2/6, seg = s2-row*6;
            u16 (*dk)[72] = plane? lKl : lKh;
            *(int4*)(&dk[row][seg*8]) = kreg[it];
            int rowv = s2>>3, segv = s2&7;
            u16 (*dv)[72] = plane? lVl : lVh;
            *(int4*)(&dv[rowv][segv*8]) = vreg[it];
        }
        __syncthreads();   // staging visible
        // QK^T (hi*hi + hi*lo + lo*hi)
        f32x4 sc[4];
        #pragma unroll
        for (int nf=0;nf<4;nf++){
            short8 bh0 = *(const short8*)(&lKh[nf*16+fr][fg*8]);
            short8 bh1 = *(const short8*)(&lKh[nf*16+fr][32+fg*8]);
            short8 bl0 = *(const short8*)(&lKl[nf*16+fr][fg*8]);
            short8 bl1 = *(const short8*)(&lKl[nf*16+fr][32+fg*8]);
            f32x4 a = (f32x4){0.f,0.f,0.f,0.f};
            a = __builtin_amdgcn_mfma_f32_16x16x32_bf16(aqh0, bh0, a, 0,0,0);
            a = __builtin_amdgcn_mfma_f32_16x16x32_bf16(aqh1, bh1, a, 0,0,0);
            a = __builtin_amdgcn_mfma_f32_16x16x32_bf16(aqh0, bl0, a, 0,0,0);
            a = __builtin_amdgcn_mfma_f32_16x16x32_bf16(aqh1, bl1, a, 0,0,0);
            a = __builtin_amdgcn_mfma_f32_16x16x32_bf16(aql0, bh0, a, 0,0,0);
            a = __builtin_amdgcn_mfma_f32_16x16x32_bf16(aql1, bh1, a, 0,0,0);
            sc[nf]=a;
        }
        // + pair bias, online softmax (rows spread over fr lanes, width-16)
        float mn[4];
        #pragma unroll
        for (int r=0;r<4;r++){
            float v0 = sc[0][r]+bf2f(pbv[r][0]);
            float v1 = sc[1][r]+bf2f(pbv[r][1]);
            float v2 = sc[2][r]+bf2f(pbv[r][2]);
            float v3 = sc[3][r]+bf2f(pbv[r][3]);
            sc[0][r]=v0; sc[1][r]=v1; sc[2][r]=v2; sc[3][r]=v3;
            float mx = fmaxf(fmaxf(v0,v1),fmaxf(v2,v3));
            mx = fmaxf(mx, __shfl_xor(mx,1,64));
            mx = fmaxf(mx, __shfl_xor(mx,2,64));
            mx = fmaxf(mx, __shfl_xor(mx,4,64));
            mx = fmaxf(mx, __shfl_xor(mx,8,64));
            mn[r]=mx;
        }
        #pragma unroll
        for (int r=0;r<4;r++){
            float mnew = fmaxf(m[r], mn[r]);
            float corr = __expf(m[r]-mnew);
            m[r]=mnew;
            float ps=0.f;
            #pragma unroll
            for (int nf=0;nf<4;nf++){
                float p = __expf(sc[nf][r]-mnew);
                u16 pu = f2bf(p);
                ps += bf2f(pu);
                lP[w][fg*4+r][nf*16+fr] = pu;
            }
            // l[r] is a per-lane PARTIAL row-sum (this lane's 4 columns);
            // corr is lane-uniform within the row group, so the linear
            // recurrence commutes with the final cross-lane sum (epilogue).
            l[r] = l[r]*corr + ps;
            acc_o[0][r]*=corr; acc_o[1][r]*=corr; acc_o[2][r]*=corr;
        }
        // PV (per-wave P tile; same-wave LDS dependency)
        short8 pa0 = *(const short8*)(&lP[w][fr][fg*8]);
        short8 pa1 = *(const short8*)(&lP[w][fr][32+fg*8]);
        #pragma unroll
        for (int cf=0;cf<3;cf++){
            short8 vh0 = *(const short8*)(&lVh[cf*16+fr][fg*8]);
            short8 vh1 = *(const short8*)(&lVh[cf*16+fr][32+fg*8]);
            short8 vl0 = *(const short8*)(&lVl[cf*16+fr][fg*8]);
            short8 vl1 = *(const short8*)(&lVl[cf*16+fr][32+fg*8]);
            acc_o[cf] = __builtin_amdgcn_mfma_f32_16x16x32_bf16(pa0, vh0, acc_o[cf], 0,0,0);
            acc_o[cf] = __builtin_amdgcn_mfma_f32_16x16x32_bf16(pa1, vh1, acc_o[cf], 0,0,0);
            acc_o[cf] = __builtin_amdgcn_mfma_f32_16x16x32_bf16(pa0, vl0, acc_o[cf], 0,0,0);
            acc_o[cf] = __builtin_amdgcn_mfma_f32_16x16x32_bf16(pa1, vl1, acc_o[cf], 0,0,0);
        }
    }
    // epilogue: reduce the lane-partial l across the 16 fr-lanes (FIX),
    // then O/l * gate -> og split planes
    float rl[4];
    #pragma unroll
    for (int r=0;r<4;r++){
        float lv = l[r];
        lv += __shfl_xor(lv,1,64);
        lv += __shfl_xor(lv,2,64);
        lv += __shfl_xor(lv,4,64);
        lv += __shfl_xor(lv,8,64);
        rl[r] = 1.f/lv;
    }
    #pragma unroll
    for (int cf=0;cf<3;cf++){
        #pragma unroll
        for (int r=0;r<4;r++){
            size_t orow = ((size_t)(s*NN + m0 + w*16 + fg*4 + r))*DIMM + h*CH + cf*16 + fr;
            float val = acc_o[cf][r]*rl[r] * g[orow];
            u16 hh,ll; bfsplit(val,hh,ll);
            oghi[orow]=hh; oglo[orow]=ll;
        }
    }
}

// ---------------------------------------------------------------------------
extern "C" void kernel_launch(void* const* d_in, const int* in_sizes, int n_in,
                              void* d_out, int out_size, void* d_ws, size_t ws_size,
                              hipStream_t stream)
{
    const float* srep   = (const float*)d_in[0];
    const float* sproj  = (const float*)d_in[1];
    const float* pair   = (const float*)d_in[2];
    const float* mask   = (const float*)d_in[3];
    const float* s_w    = (const float*)d_in[4];
    const float* gate_w = (const float*)d_in[5];
    const float* gate_b = (const float*)d_in[6];
    const float* skip_w = (const float*)d_in[7];
    const float* wq     = (const float*)d_in[8];
    const float* wk     = (const float*)d_in[9];
    const float* wv     = (const float*)d_in[10];
    const float* w_gate = (const float*)d_in[11];
    const float* b_gate = (const float*)d_in[12];
    const float* wo     = (const float*)d_in[13];
    const float* bo     = (const float*)d_in[14];
    const float* plnw   = (const float*)d_in[15];
    const float* plnb   = (const float*)d_in[16];
    const float* w_pair = (const float*)d_in[17];
    const float* w_out  = (const float*)d_in[18];
    const float* b_out  = (const float*)d_in[19];
    float* out = (float*)d_out;

    const size_t T  = (size_t)NROWS*DIMM;       // 1,572,864
    const size_t W  = (size_t)DIMM*DIMM;        // 589,824
    const size_t PB = (size_t)HEADS*NN*NN;      // 16,777,216

    char* p = (char*)d_ws;
    float* a_ln = (float*)p; p += T*4;
    float* g    = (float*)p; p += T*4;
    float* wpc  = (float*)p; p += 2048*4;
    float* csb  = (float*)p; p += 32*4;
    u16* shi  = (u16*)p; p += T*2;
    u16* slo  = (u16*)p; p += T*2;
    u16* ahi  = (u16*)p; p += T*2;
    u16* alo  = (u16*)p; p += T*2;
    u16* oghi = (u16*)p; p += T*2;
    u16* oglo = (u16*)p; p += T*2;
    u16* o2hi = (u16*)p; p += T*2;
    u16* o2lo = (u16*)p; p += T*2;
    u16* qah  = (u16*)p; p += T*2;
    u16* qal  = (u16*)p; p += T*2;
    u16* kah  = (u16*)p; p += T*2;
    u16* kal  = (u16*)p; p += T*2;
    u16* vth  = (u16*)p; p += T*2;
    u16* vtl  = (u16*)p; p += T*2;
    u16* pbias= (u16*)p; p += PB*2;
    u16* wt   = (u16*)p; p += 16*W*2;

    #define WH(i) (wt + (size_t)(i)*2*W)
    #define WL(i) (wt + (size_t)(i)*2*W + W)

    k_wsplit<<<dim3(12,12,8), 256, 0, stream>>>(
        gate_w, skip_w, wq, wk, wv, w_gate, wo, w_out, wt);
    k_ln_single<<<NROWS, 256, 0, stream>>>(srep, sproj, s_w, a_ln, shi, slo);
    k_pair_pre<<<1, 256, 0, stream>>>(plnw, plnb, w_pair, wpc, csb);
    k_pair_bias<<<(NN*NN)/256, 256, 0, stream>>>(pair, wpc, csb, mask, pbias);

    dim3 gg(NROWS/64, DIMM/64);
    // G1: a = sigm(s@gate_w + gate_b)*a_ln + s@skip_w  -> a planes
    k_gemm<2,0><<<gg, 256, 0, stream>>>(shi, slo, WH(0), WL(0), WH(1), WL(1),
                                        gate_b, a_ln, nullptr, nullptr, ahi, alo);
    // G2: q = (a@wq)*scale -> qa planes; k = a@wk -> ka planes
    k_gemm<2,1><<<gg, 256, 0, stream>>>(ahi, alo, WH(2), WL(2), WH(3), WL(3),
                                        nullptr, nullptr, (float*)kah, (float*)kal, qah, qal);
    // G3: v = a@wv -> vT planes; g = sigm(a@w_gate + b_gate) f32
    k_gemm<2,2><<<gg, 256, 0, stream>>>(ahi, alo, WH(4), WL(4), WH(5), WL(5),
                                        b_gate, nullptr, g, nullptr, vth, vtl);

    k_attn<<<dim3(NN/64, 2*HEADS), 256, 0, stream>>>(
        qah, qal, kah, kal, vth, vtl, pbias, g, oghi, oglo);

    // G4: o2 = og@wo + bo -> o2 planes
    k_gemm<1,3><<<gg, 256, 0, stream>>>(oghi, oglo, WH(6), WL(6), nullptr, nullptr,
                                        bo, nullptr, nullptr, nullptr, o2hi, o2lo);
    // G5: out = sigm(o2@w_out + b_out) * o2
    k_gemm<1,4><<<gg, 256, 0, stream>>>(o2hi, o2lo, WH(7), WL(7), nullptr, nullptr,
                                        b_out, nullptr, out, nullptr, nullptr, nullptr);
    #undef WH
    #undef WL
}